// Round 4
// baseline (546.095 us; speedup 1.0000x reference)
//
#include <hip/hip_runtime.h>
#include <hip/hip_bf16.h>

// MoE head: router(top2 of 8) -> gather/compact -> GEMM1+GELU -> GEMM2(split-K) -> combine+residual+LN
// N=4096 tokens, H=1024, F=4096, E=8, TOP_K=2. bf16 MFMA compute, fp32 router/epilogues.
// R4: reg-staged LDS (T14) with padded stride-40 rows (conflict-free reads);
//     W1/W2 fp32->bf16 convert + transpose fused into GEMM B-staging (transp kernels deleted).

typedef unsigned short u16;
typedef unsigned int u32;
typedef __attribute__((ext_vector_type(4))) float f32x4;
typedef __attribute__((ext_vector_type(8))) short s16x8;
typedef __attribute__((ext_vector_type(8))) unsigned short u16x8;

#define LDSTR 40   // padded LDS row stride in bf16 elems (80B: 16B-aligned, 2-way banks)

__device__ __forceinline__ u16 f2bf(float f) {
    union { float f; u32 u; } v; v.f = f;
    u32 u = v.u;
    return (u16)((u + 0x7fffu + ((u >> 16) & 1u)) >> 16);
}

// fast GELU: v * sigmoid(1.59577v + 0.0713548v^3)
__device__ __forceinline__ float gelu_f(float v) {
    const float u = v * (0.7978845608f + 0.0356774081f * v * v);
    const float t = __expf(-2.0f * u);
    return v * __builtin_amdgcn_rcpf(1.0f + t);
}

// ---------------- K0: zero counts+cursors (16 ints) ----------------
__global__ void k_init(int* cc) { if (threadIdx.x < 16) cc[threadIdx.x] = 0; }

// ---------------- K1: router (fp32) + x->bf16 convert ----------------
__global__ __launch_bounds__(256) void k_router(
    const float* __restrict__ x, const float* __restrict__ rw, const float* __restrict__ rb,
    u16* __restrict__ xb, int* __restrict__ eidx, float* __restrict__ wgt, int* __restrict__ counts)
{
    const int wav = threadIdx.x >> 6, lane = threadIdx.x & 63;
    const int t = blockIdx.x * 4 + wav;
    const float* xt = x + (size_t)t * 1024;
    float acc[8] = {0.f,0.f,0.f,0.f,0.f,0.f,0.f,0.f};
    #pragma unroll
    for (int c = 0; c < 4; c++) {
        const int base = c * 256 + lane * 4;
        const float4 xv = *(const float4*)(xt + base);
        ushort4 pk;
        pk.x = f2bf(xv.x); pk.y = f2bf(xv.y); pk.z = f2bf(xv.z); pk.w = f2bf(xv.w);
        *(ushort4*)(xb + (size_t)t * 1024 + base) = pk;
        #pragma unroll
        for (int e = 0; e < 8; e++) {
            const float4 wv = *(const float4*)(rw + e * 1024 + base);
            acc[e] += xv.x * wv.x + xv.y * wv.y + xv.z * wv.z + xv.w * wv.w;
        }
    }
    #pragma unroll
    for (int e = 0; e < 8; e++) {
        #pragma unroll
        for (int s = 32; s; s >>= 1) acc[e] += __shfl_xor(acc[e], s);
    }
    if (lane == 0) {
        float v0 = -3e38f, v1 = -3e38f; int i0 = 0, i1 = 0;
        #pragma unroll
        for (int e = 0; e < 8; e++) {
            const float l = acc[e] + rb[e];
            if (l > v0) { v1 = v0; i1 = i0; v0 = l; i0 = e; }
            else if (l > v1) { v1 = l; i1 = e; }
        }
        const float w0 = 1.0f / (1.0f + expf(v1 - v0));
        eidx[2 * t] = i0; eidx[2 * t + 1] = i1;
        wgt[2 * t] = w0; wgt[2 * t + 1] = 1.0f - w0;
        atomicAdd(&counts[i0], 1); atomicAdd(&counts[i1], 1);
    }
}

// ---------------- K2: exclusive prefix of 8 counts ----------------
__global__ void k_offsets(const int* __restrict__ counts, int* __restrict__ offsets) {
    if (threadIdx.x == 0) {
        int s = 0;
        for (int e = 0; e < 8; e++) { offsets[e] = s; s += counts[e]; }
        offsets[8] = s;
    }
}

// ---------------- K3: place assignments into compacted row list ----------------
__global__ __launch_bounds__(256) void k_place(
    const int* __restrict__ eidx, const int* __restrict__ offsets, int* __restrict__ cursors,
    int* __restrict__ rows, int* __restrict__ pos_of)
{
    const int a = blockIdx.x * 256 + threadIdx.x;   // 8192 assignments
    const int e = eidx[a];
    const int pos = offsets[e] + atomicAdd(&cursors[e], 1);
    rows[pos] = a >> 1;
    pos_of[a] = pos;
}

// ---------------- K5: grouped GEMM1 + bias + fast GELU -> h (bf16) ----------------
// A = gathered xb rows (bf16) [cnt x 1024]; B = W1[e] fp32 [1024 k][4096 n], transposed+converted in staging.
// 8192 blocks flat; swz -> (e, x=n-tile of 32, y=row-tile of 32, y fastest)
__global__ __launch_bounds__(256, 3) void k_gemm1(
    const u16* __restrict__ xb, const float* __restrict__ W1, const float* __restrict__ b1,
    u16* __restrict__ hbuf, const int* __restrict__ rows, const int* __restrict__ offsets)
{
    const int fid = blockIdx.x;
    const int swz = (fid & 7) * 1024 + (fid >> 3);   // bijective, nwg=8192
    const int y = swz & 31, xx = (swz >> 5) & 31, e = swz >> 10;

    const int off = offsets[e], cnt = offsets[e + 1] - off;
    const int row0 = y * 128;
    if (row0 >= cnt) return;
    const int n0 = xx * 128;
    const int tid = threadIdx.x;
    const int lane = tid & 63, wav = tid >> 6, lane15 = lane & 15;

    __shared__ u16 AtP[2][128][LDSTR];
    __shared__ u16 BtP[2][128][LDSTR];

    // A staging: thread -> row tid>>1 (0..127), half tid&1 (16 elems)
    const int arow = tid >> 1, ahalf = tid & 1;
    const int tok = rows[off + min(row0 + arow, cnt - 1)];
    const u16* a_row = xb + (size_t)tok * 1024 + ahalf * 16;
    // B staging: wave wav handles k-rows wav*8..+7; lane = n-pair (n = n0 + lane*2)
    const float* b_row = W1 + ((size_t)e * 1024 + wav * 8) * 4096 + n0 + lane * 2;

    s16x8 aw0, aw1;
    float2 bw[8];

    auto loadA = [&](int k0) {
        aw0 = *(const s16x8*)(a_row + k0);
        aw1 = *(const s16x8*)(a_row + k0 + 8);
    };
    auto loadB = [&](int k0) {
        #pragma unroll
        for (int i = 0; i < 8; i++)
            bw[i] = *(const float2*)(b_row + (size_t)(k0 + i) * 4096);
    };
    auto writeA = [&](int b) {
        *(s16x8*)(&AtP[b][arow][ahalf * 16]) = aw0;
        *(s16x8*)(&AtP[b][arow][ahalf * 16 + 8]) = aw1;
    };
    auto writeB = [&](int b) {
        s16x8 v0, v1;
        #pragma unroll
        for (int i = 0; i < 8; i++) { v0[i] = (short)f2bf(bw[i].x); v1[i] = (short)f2bf(bw[i].y); }
        *(s16x8*)(&BtP[b][lane * 2][wav * 8]) = v0;
        *(s16x8*)(&BtP[b][lane * 2 + 1][wav * 8]) = v1;
    };

    f32x4 acc[4][4] = {};
    const int wr = wav >> 1, wc = wav & 1;
    const int koff = (lane >> 4) * 8;

    auto compute = [&](int b) {
        const u16* Ap = &AtP[b][wr * 64 + lane15][koff];
        const u16* Bp = &BtP[b][wc * 64 + lane15][koff];
        s16x8 af[4], bfr[4];
        #pragma unroll
        for (int i = 0; i < 4; i++) {
            af[i]  = *(const s16x8*)(Ap + i * 16 * LDSTR);
            bfr[i] = *(const s16x8*)(Bp + i * 16 * LDSTR);
        }
        #pragma unroll
        for (int mi = 0; mi < 4; mi++)
            #pragma unroll
            for (int ni = 0; ni < 4; ni++)
                acc[mi][ni] = __builtin_amdgcn_mfma_f32_16x16x32_bf16(af[mi], bfr[ni], acc[mi][ni], 0, 0, 0);
    };

    loadA(0); loadB(0);
    writeA(0); writeB(0);
    __syncthreads();
    int cur = 0;
    for (int k0 = 32; k0 < 1024; k0 += 32) {
        loadA(k0); loadB(k0);      // issue next tile's global loads
        compute(cur);              // MFMA hides the load latency
        writeA(cur ^ 1); writeB(cur ^ 1);
        __syncthreads();
        cur ^= 1;
    }
    compute(cur);

    const int rb4 = (lane >> 4) * 4;
    const int colbase = n0 + wc * 64 + lane15;
    float bias[4];
    #pragma unroll
    for (int ni = 0; ni < 4; ni++) bias[ni] = b1[e * 4096 + colbase + ni * 16];
    #pragma unroll
    for (int mi = 0; mi < 4; mi++) {
        #pragma unroll
        for (int j = 0; j < 4; j++) {
            const int lrow = wr * 64 + mi * 16 + rb4 + j;
            if (row0 + lrow < cnt) {
                const size_t gr = (size_t)(off + row0 + lrow);
                #pragma unroll
                for (int ni = 0; ni < 4; ni++) {
                    const float v = acc[mi][ni][j] + bias[ni];
                    hbuf[gr * 4096 + colbase + ni * 16] = f2bf(gelu_f(v));
                }
            }
        }
    }
}

// ---------------- K6: grouped GEMM2 (split-K x2) + bias -> y0/y1 (fp32) ----------------
// A = hbuf rows (bf16, contiguous); B = W2[e] fp32 [4096 k][1024 n], transposed+converted in staging.
// 4096 blocks flat; swz -> (z=e*2+kh, x=n-tile of 8, y=row-tile of 32, y fastest)
__global__ __launch_bounds__(256, 3) void k_gemm2(
    const u16* __restrict__ hbuf, const float* __restrict__ W2, const float* __restrict__ b2,
    float* __restrict__ y0, float* __restrict__ y1, const int* __restrict__ offsets)
{
    const int fid = blockIdx.x;
    const int swz = (fid & 7) * 512 + (fid >> 3);    // bijective, nwg=4096
    const int y = swz & 31, xx = (swz >> 5) & 7, z = swz >> 8;
    const int e = z >> 1, kh = z & 1;

    const int off = offsets[e], cnt = offsets[e + 1] - off;
    const int row0 = y * 128;
    if (row0 >= cnt) return;
    const int n0 = xx * 128;
    const int tid = threadIdx.x;
    const int lane = tid & 63, wav = tid >> 6, lane15 = lane & 15;
    const int kbase = kh * 2048;

    __shared__ u16 AtP[2][128][LDSTR];
    __shared__ u16 BtP[2][128][LDSTR];

    const int arow = tid >> 1, ahalf = tid & 1;
    const u16* a_row = hbuf + (size_t)(off + min(row0 + arow, cnt - 1)) * 4096 + kbase + ahalf * 16;
    const float* b_row = W2 + ((size_t)e * 4096 + kbase + wav * 8) * 1024 + n0 + lane * 2;

    s16x8 aw0, aw1;
    float2 bw[8];

    auto loadA = [&](int k0) {
        aw0 = *(const s16x8*)(a_row + k0);
        aw1 = *(const s16x8*)(a_row + k0 + 8);
    };
    auto loadB = [&](int k0) {
        #pragma unroll
        for (int i = 0; i < 8; i++)
            bw[i] = *(const float2*)(b_row + (size_t)(k0 + i) * 1024);
    };
    auto writeA = [&](int b) {
        *(s16x8*)(&AtP[b][arow][ahalf * 16]) = aw0;
        *(s16x8*)(&AtP[b][arow][ahalf * 16 + 8]) = aw1;
    };
    auto writeB = [&](int b) {
        s16x8 v0, v1;
        #pragma unroll
        for (int i = 0; i < 8; i++) { v0[i] = (short)f2bf(bw[i].x); v1[i] = (short)f2bf(bw[i].y); }
        *(s16x8*)(&BtP[b][lane * 2][wav * 8]) = v0;
        *(s16x8*)(&BtP[b][lane * 2 + 1][wav * 8]) = v1;
    };

    f32x4 acc[4][4] = {};
    const int wr = wav >> 1, wc = wav & 1;
    const int koff = (lane >> 4) * 8;

    auto compute = [&](int b) {
        const u16* Ap = &AtP[b][wr * 64 + lane15][koff];
        const u16* Bp = &BtP[b][wc * 64 + lane15][koff];
        s16x8 af[4], bfr[4];
        #pragma unroll
        for (int i = 0; i < 4; i++) {
            af[i]  = *(const s16x8*)(Ap + i * 16 * LDSTR);
            bfr[i] = *(const s16x8*)(Bp + i * 16 * LDSTR);
        }
        #pragma unroll
        for (int mi = 0; mi < 4; mi++)
            #pragma unroll
            for (int ni = 0; ni < 4; ni++)
                acc[mi][ni] = __builtin_amdgcn_mfma_f32_16x16x32_bf16(af[mi], bfr[ni], acc[mi][ni], 0, 0, 0);
    };

    loadA(0); loadB(0);
    writeA(0); writeB(0);
    __syncthreads();
    int cur = 0;
    for (int k0 = 32; k0 < 2048; k0 += 32) {
        loadA(k0); loadB(k0);
        compute(cur);
        writeA(cur ^ 1); writeB(cur ^ 1);
        __syncthreads();
        cur ^= 1;
    }
    compute(cur);

    float* yy = kh ? y1 : y0;
    const int rb4 = (lane >> 4) * 4;
    const int colbase = n0 + wc * 64 + lane15;
    float bias[4];
    #pragma unroll
    for (int ni = 0; ni < 4; ni++) bias[ni] = kh ? 0.f : b2[e * 1024 + colbase + ni * 16];
    #pragma unroll
    for (int mi = 0; mi < 4; mi++) {
        #pragma unroll
        for (int j = 0; j < 4; j++) {
            const int lrow = wr * 64 + mi * 16 + rb4 + j;
            if (row0 + lrow < cnt) {
                const size_t gr = (size_t)(off + row0 + lrow);
                #pragma unroll
                for (int ni = 0; ni < 4; ni++)
                    yy[gr * 1024 + colbase + ni * 16] = acc[mi][ni][j] + bias[ni];
            }
        }
    }
}

// ---------------- K7: combine (w0*(y0+y1) + residual) + LayerNorm ----------------
__global__ __launch_bounds__(256) void k_combine(
    const float* __restrict__ x, const float* __restrict__ y0, const float* __restrict__ y1,
    const int* __restrict__ pos_of, const float* __restrict__ wgt,
    const float* __restrict__ gamma, const float* __restrict__ beta,
    float* __restrict__ out)
{
    const int t = blockIdx.x;
    const int tid = threadIdx.x;
    const int p0 = pos_of[2 * t], p1 = pos_of[2 * t + 1];
    const float w0 = wgt[2 * t], w1 = wgt[2 * t + 1];
    const int j4 = tid * 4;
    const float4 xv = *(const float4*)(x + (size_t)t * 1024 + j4);
    const float4 ya0 = *(const float4*)(y0 + (size_t)p0 * 1024 + j4);
    const float4 yb0 = *(const float4*)(y1 + (size_t)p0 * 1024 + j4);
    const float4 ya1 = *(const float4*)(y0 + (size_t)p1 * 1024 + j4);
    const float4 yb1 = *(const float4*)(y1 + (size_t)p1 * 1024 + j4);
    float a0 = xv.x + w0 * (ya0.x + yb0.x) + w1 * (ya1.x + yb1.x);
    float a1 = xv.y + w0 * (ya0.y + yb0.y) + w1 * (ya1.y + yb1.y);
    float a2 = xv.z + w0 * (ya0.z + yb0.z) + w1 * (ya1.z + yb1.z);
    float a3 = xv.w + w0 * (ya0.w + yb0.w) + w1 * (ya1.w + yb1.w);
    float s = a0 + a1 + a2 + a3;
    float q = a0 * a0 + a1 * a1 + a2 * a2 + a3 * a3;
    #pragma unroll
    for (int o = 32; o; o >>= 1) { s += __shfl_xor(s, o); q += __shfl_xor(q, o); }
    __shared__ float ls[4], lq[4];
    const int wav = tid >> 6, lane = tid & 63;
    if (lane == 0) { ls[wav] = s; lq[wav] = q; }
    __syncthreads();
    s = ls[0] + ls[1] + ls[2] + ls[3];
    q = lq[0] + lq[1] + lq[2] + lq[3];
    const float mu = s * (1.0f / 1024.0f);
    const float var = q * (1.0f / 1024.0f) - mu * mu;
    const float rs = rsqrtf(var + 1e-5f);
    const float4 g = *(const float4*)(gamma + j4);
    const float4 b = *(const float4*)(beta + j4);
    float4 o4;
    o4.x = (a0 - mu) * rs * g.x + b.x;
    o4.y = (a1 - mu) * rs * g.y + b.y;
    o4.z = (a2 - mu) * rs * g.z + b.z;
    o4.w = (a3 - mu) * rs * g.w + b.w;
    *(float4*)(out + (size_t)t * 1024 + j4) = o4;
}

extern "C" void kernel_launch(void* const* d_in, const int* in_sizes, int n_in,
                              void* d_out, int out_size, void* d_ws, size_t ws_size,
                              hipStream_t stream) {
    const float* x     = (const float*)d_in[0];   // [2,2048,1024]
    const float* rw    = (const float*)d_in[1];   // [8,1024]
    const float* rb    = (const float*)d_in[2];   // [8]
    const float* W1    = (const float*)d_in[3];   // [8,1024,4096]
    const float* b1    = (const float*)d_in[4];   // [8,4096]
    const float* W2    = (const float*)d_in[5];   // [8,4096,1024]
    const float* b2    = (const float*)d_in[6];   // [8,1024]
    const float* gamma = (const float*)d_in[7];   // [1024]
    const float* beta  = (const float*)d_in[8];   // [1024]
    float* out = (float*)d_out;

    // workspace carve (256B aligned)
    char* p = (char*)d_ws;
    auto alloc = [&](size_t bytes) { char* r = p; p += (bytes + 255) & ~(size_t)255; return r; };
    int*   counts  = (int*)alloc(16 * sizeof(int));      // counts[0..7], cursors[8..15]
    int*   cursors = counts + 8;
    int*   offsets = (int*)alloc(9 * sizeof(int));
    int*   eidx    = (int*)alloc(8192 * sizeof(int));
    float* wgt     = (float*)alloc(8192 * sizeof(float));
    int*   pos_of  = (int*)alloc(8192 * sizeof(int));
    int*   rows    = (int*)alloc(8192 * sizeof(int));
    u16*   xb      = (u16*)alloc((size_t)4096 * 1024 * 2);
    u16*   hbuf    = (u16*)alloc((size_t)8192 * 4096 * 2);
    float* y0      = (float*)alloc((size_t)8192 * 1024 * 4);
    float* y1      = (float*)alloc((size_t)8192 * 1024 * 4);

    hipLaunchKernelGGL(k_init, dim3(1), dim3(64), 0, stream, counts);
    hipLaunchKernelGGL(k_router, dim3(1024), dim3(256), 0, stream, x, rw, rb, xb, eidx, wgt, counts);
    hipLaunchKernelGGL(k_offsets, dim3(1), dim3(64), 0, stream, counts, offsets);
    hipLaunchKernelGGL(k_place, dim3(32), dim3(256), 0, stream, eidx, offsets, cursors, rows, pos_of);
    hipLaunchKernelGGL(k_gemm1, dim3(8192), dim3(256), 0, stream, xb, W1, b1, hbuf, rows, offsets);
    hipLaunchKernelGGL(k_gemm2, dim3(4096), dim3(256), 0, stream, hbuf, W2, b2, y0, y1, offsets);
    hipLaunchKernelGGL(k_combine, dim3(4096), dim3(256), 0, stream, x, y0, y1, pos_of, wgt, gamma, beta, out);
}

// Round 5
// 519.948 us; speedup vs baseline: 1.0503x; 1.0503x over previous
//
#include <hip/hip_runtime.h>
#include <hip/hip_bf16.h>

// MoE head: router(top2 of 8) -> compact -> GEMM1+GELU -> GEMM2(split-K) -> combine+residual+LN
// R5: persistent grouped GEMMs (4 blocks/CU, per-XCD atomic tile cursors, no wasted blocks),
//     R3-style global_load_lds dbuf core, bf16 y partials.

typedef unsigned short u16;
typedef unsigned int u32;
typedef __attribute__((ext_vector_type(4))) float f32x4;
typedef __attribute__((ext_vector_type(8))) short s16x8;
typedef __attribute__((ext_vector_type(8))) unsigned short u16x8;

#define GLD16(gp, lp) __builtin_amdgcn_global_load_lds( \
    (const __attribute__((address_space(1))) void*)(gp), \
    (__attribute__((address_space(3))) void*)(lp), 16, 0, 0)

__device__ __forceinline__ u16 f2bf(float f) {
    union { float f; u32 u; } v; v.f = f;
    u32 u = v.u;
    return (u16)((u + 0x7fffu + ((u >> 16) & 1u)) >> 16);
}
__device__ __forceinline__ float bf2f(u16 h) {
    union { u32 u; float f; } v; v.u = ((u32)h) << 16; return v.f;
}

// fast GELU: v * sigmoid(1.59577v + 0.0713548v^3)
__device__ __forceinline__ float gelu_f(float v) {
    const float u = v * (0.7978845608f + 0.0356774081f * v * v);
    const float t = __expf(-2.0f * u);
    return v * __builtin_amdgcn_rcpf(1.0f + t);
}

// ---------------- K0: zero counts/cursors/work-cursors (32 ints) ----------------
__global__ void k_init(int* cc) { if (threadIdx.x < 32) cc[threadIdx.x] = 0; }

// ---------------- K1: router (fp32) + x->bf16 convert ----------------
__global__ __launch_bounds__(256) void k_router(
    const float* __restrict__ x, const float* __restrict__ rw, const float* __restrict__ rb,
    u16* __restrict__ xb, int* __restrict__ eidx, float* __restrict__ wgt, int* __restrict__ counts)
{
    const int wav = threadIdx.x >> 6, lane = threadIdx.x & 63;
    const int t = blockIdx.x * 4 + wav;
    const float* xt = x + (size_t)t * 1024;
    float acc[8] = {0.f,0.f,0.f,0.f,0.f,0.f,0.f,0.f};
    #pragma unroll
    for (int c = 0; c < 4; c++) {
        const int base = c * 256 + lane * 4;
        const float4 xv = *(const float4*)(xt + base);
        ushort4 pk;
        pk.x = f2bf(xv.x); pk.y = f2bf(xv.y); pk.z = f2bf(xv.z); pk.w = f2bf(xv.w);
        *(ushort4*)(xb + (size_t)t * 1024 + base) = pk;
        #pragma unroll
        for (int e = 0; e < 8; e++) {
            const float4 wv = *(const float4*)(rw + e * 1024 + base);
            acc[e] += xv.x * wv.x + xv.y * wv.y + xv.z * wv.z + xv.w * wv.w;
        }
    }
    #pragma unroll
    for (int e = 0; e < 8; e++) {
        #pragma unroll
        for (int s = 32; s; s >>= 1) acc[e] += __shfl_xor(acc[e], s);
    }
    if (lane == 0) {
        float v0 = -3e38f, v1 = -3e38f; int i0 = 0, i1 = 0;
        #pragma unroll
        for (int e = 0; e < 8; e++) {
            const float l = acc[e] + rb[e];
            if (l > v0) { v1 = v0; i1 = i0; v0 = l; i0 = e; }
            else if (l > v1) { v1 = l; i1 = e; }
        }
        const float w0 = 1.0f / (1.0f + expf(v1 - v0));
        eidx[2 * t] = i0; eidx[2 * t + 1] = i1;
        wgt[2 * t] = w0; wgt[2 * t + 1] = 1.0f - w0;
        atomicAdd(&counts[i0], 1); atomicAdd(&counts[i1], 1);
    }
}

// ---------------- K2: exclusive prefix of 8 counts ----------------
__global__ void k_offsets(const int* __restrict__ counts, int* __restrict__ offsets) {
    if (threadIdx.x == 0) {
        int s = 0;
        for (int e = 0; e < 8; e++) { offsets[e] = s; s += counts[e]; }
        offsets[8] = s;
    }
}

// ---------------- K3: place assignments into compacted row list ----------------
__global__ __launch_bounds__(256) void k_place(
    const int* __restrict__ eidx, const int* __restrict__ offsets, int* __restrict__ cursors,
    int* __restrict__ rows, int* __restrict__ pos_of)
{
    const int a = blockIdx.x * 256 + threadIdx.x;   // 8192 assignments
    const int e = eidx[a];
    const int pos = offsets[e] + atomicAdd(&cursors[e], 1);
    rows[pos] = a >> 1;
    pos_of[a] = pos;
}

// ---------------- K4: transpose + fp32->bf16 (per expert), no LDS ----------------
// src [E][R][C] f32 -> dst [E][C][R] bf16 ; grid (C/64, R/32, E), block 256
__global__ __launch_bounds__(256) void k_transp(
    const float* __restrict__ src, u16* __restrict__ dst, int R, int C)
{
    const int e = blockIdx.z;
    const float* s = src + (size_t)e * R * C;
    u16* d = dst + (size_t)e * R * C;
    const int c = blockIdx.x * 64 + (threadIdx.x >> 2);
    const int r0 = blockIdx.y * 32 + (threadIdx.x & 3) * 8;
    u16x8 v;
    #pragma unroll
    for (int k = 0; k < 8; k++)
        v[k] = f2bf(s[(size_t)(r0 + k) * C + c]);
    *(u16x8*)(d + (size_t)c * R + r0) = v;
}

// shared GEMM K-step macros (R3 core): LDS [2][128][32] bf16 per operand
#define STAGE_T(b, k0) { \
    char* ad = (char*)At + (b) * 8192 + wav * 1024; \
    char* bd = (char*)Bt + (b) * 8192 + wav * 1024; \
    GLD16(a_src0 + (k0), ad); \
    GLD16(a_src1 + (k0), ad + 4096); \
    GLD16(b_src0 + (k0), bd); \
    GLD16(b_src1 + (k0), bd + 4096); }

#define COMPUTE_T(b) { \
    const u16* Abp = Ab + (b) * 4096; \
    const u16* Bbp = Bb + (b) * 4096; \
    s16x8 af[4], bfr[4]; \
    _Pragma("unroll") \
    for (int i = 0; i < 4; i++) { \
        af[i]  = *(const s16x8*)(Abp + i * 512); \
        bfr[i] = *(const s16x8*)(Bbp + i * 512); \
    } \
    _Pragma("unroll") \
    for (int mi = 0; mi < 4; mi++) \
        _Pragma("unroll") \
        for (int ni = 0; ni < 4; ni++) \
            acc[mi][ni] = __builtin_amdgcn_mfma_f32_16x16x32_bf16(af[mi], bfr[ni], acc[mi][ni], 0, 0, 0); }

// ---------------- K5: persistent grouped GEMM1 + bias + GELU -> h (bf16) ----------------
// grid 1024 (4 blocks/CU). Tiles: per expert e, ceil(cnt/128) row-tiles x 32 n-tiles,
// row-tile fastest. Per-XCD chunked dynamic cursor wk[xcd].
__global__ __launch_bounds__(256, 4) void k_gemm1(
    const u16* __restrict__ xb, const u16* __restrict__ W1t, const float* __restrict__ b1,
    u16* __restrict__ hbuf, const int* __restrict__ rows, const int* __restrict__ offsets,
    int* __restrict__ wk)
{
    const int tid = threadIdx.x;
    const int lane = tid & 63, wav = tid >> 6;
    const int xcd = blockIdx.x & 7;

    int base_e[9], rt_e[8];
    int T = 0;
    #pragma unroll
    for (int e = 0; e < 8; e++) {
        base_e[e] = T;
        const int c = offsets[e + 1] - offsets[e];
        rt_e[e] = (c + 127) >> 7;
        T += rt_e[e] * 32;
    }
    base_e[8] = T;
    const int Tx = (T + 7) >> 3;
    const int tbeg = xcd * Tx, tend = min(T, tbeg + Tx);

    __shared__ u16 At[2][128][32];
    __shared__ u16 Bt[2][128][32];
    __shared__ int s_t;

    const int wr = wav >> 1, wc = wav & 1;
    const int lane15 = lane & 15;
    const int koff = (lane >> 4) * 8;
    const int ar0 = tid >> 2, cl8 = (tid & 3) * 8;
    const u16* Ab = &At[0][wr * 64 + lane15][koff];
    const u16* Bb = &Bt[0][wc * 64 + lane15][koff];

    for (;;) {
        __syncthreads();                       // protect LDS bufs + s_t
        if (tid == 0) s_t = atomicAdd(&wk[xcd], 1);
        __syncthreads();
        const int t = tbeg + s_t;
        if (t >= tend) break;

        int e = 0;
        #pragma unroll
        for (int q = 0; q < 7; q++) if (t >= base_e[q + 1]) e = q + 1;
        const int idx = t - base_e[e];
        const int rte = rt_e[e];
        const int nt = idx / rte, rt = idx - nt * rte;

        const int off = offsets[e], cnt = offsets[e + 1] - off;
        const int row0 = rt * 128, n0 = nt * 128;

        const int t0 = rows[off + min(row0 + ar0, cnt - 1)];
        const int t1 = rows[off + min(row0 + ar0 + 64, cnt - 1)];
        const u16* a_src0 = xb + (size_t)t0 * 1024 + cl8;
        const u16* a_src1 = xb + (size_t)t1 * 1024 + cl8;
        const u16* b_src0 = W1t + ((size_t)e * 4096 + n0 + ar0) * 1024 + cl8;
        const u16* b_src1 = b_src0 + (size_t)64 * 1024;

        f32x4 acc[4][4] = {};
        STAGE_T(0, 0);
        __syncthreads();
        int b = 0;
        for (int k0 = 32; k0 < 1024; k0 += 32) {
            STAGE_T(b ^ 1, k0);
            COMPUTE_T(b);
            __syncthreads();
            b ^= 1;
        }
        COMPUTE_T(b);

        const int rb4 = (lane >> 4) * 4;
        const int colbase = n0 + wc * 64 + lane15;
        float bias[4];
        #pragma unroll
        for (int ni = 0; ni < 4; ni++) bias[ni] = b1[e * 4096 + colbase + ni * 16];
        #pragma unroll
        for (int mi = 0; mi < 4; mi++) {
            #pragma unroll
            for (int j = 0; j < 4; j++) {
                const int lrow = wr * 64 + mi * 16 + rb4 + j;
                if (row0 + lrow < cnt) {
                    const size_t gr = (size_t)(off + row0 + lrow);
                    #pragma unroll
                    for (int ni = 0; ni < 4; ni++) {
                        const float v = acc[mi][ni][j] + bias[ni];
                        hbuf[gr * 4096 + colbase + ni * 16] = f2bf(gelu_f(v));
                    }
                }
            }
        }
    }
}

// ---------------- K6: persistent grouped GEMM2 (split-K x2) + bias -> y0/y1 (bf16) ----------------
// Tiles per expert: ceil(cnt/128) x (8 n-tiles x 2 kh), row-tile fastest.
__global__ __launch_bounds__(256, 4) void k_gemm2(
    const u16* __restrict__ hbuf, const u16* __restrict__ W2t, const float* __restrict__ b2,
    u16* __restrict__ y0b, u16* __restrict__ y1b, const int* __restrict__ offsets,
    int* __restrict__ wk)
{
    const int tid = threadIdx.x;
    const int lane = tid & 63, wav = tid >> 6;
    const int xcd = blockIdx.x & 7;

    int base_e[9], rt_e[8];
    int T = 0;
    #pragma unroll
    for (int e = 0; e < 8; e++) {
        base_e[e] = T;
        const int c = offsets[e + 1] - offsets[e];
        rt_e[e] = (c + 127) >> 7;
        T += rt_e[e] * 16;
    }
    base_e[8] = T;
    const int Tx = (T + 7) >> 3;
    const int tbeg = xcd * Tx, tend = min(T, tbeg + Tx);

    __shared__ u16 At[2][128][32];
    __shared__ u16 Bt[2][128][32];
    __shared__ int s_t;

    const int wr = wav >> 1, wc = wav & 1;
    const int lane15 = lane & 15;
    const int koff = (lane >> 4) * 8;
    const int ar0 = tid >> 2, cl8 = (tid & 3) * 8;
    const u16* Ab = &At[0][wr * 64 + lane15][koff];
    const u16* Bb = &Bt[0][wc * 64 + lane15][koff];

    for (;;) {
        __syncthreads();
        if (tid == 0) s_t = atomicAdd(&wk[xcd], 1);
        __syncthreads();
        const int t = tbeg + s_t;
        if (t >= tend) break;

        int e = 0;
        #pragma unroll
        for (int q = 0; q < 7; q++) if (t >= base_e[q + 1]) e = q + 1;
        const int idx = t - base_e[e];
        const int rte = rt_e[e];
        const int nk = idx / rte, rt = idx - nk * rte;
        const int nt = nk >> 1, kh = nk & 1;

        const int off = offsets[e], cnt = offsets[e + 1] - off;
        const int row0 = rt * 128, n0 = nt * 128;
        const int kbase = kh * 2048;

        const u16* a_src0 = hbuf + (size_t)(off + min(row0 + ar0, cnt - 1)) * 4096 + kbase + cl8;
        const u16* a_src1 = hbuf + (size_t)(off + min(row0 + ar0 + 64, cnt - 1)) * 4096 + kbase + cl8;
        const u16* b_src0 = W2t + ((size_t)e * 1024 + n0 + ar0) * 4096 + kbase + cl8;
        const u16* b_src1 = b_src0 + (size_t)64 * 4096;

        f32x4 acc[4][4] = {};
        STAGE_T(0, 0);
        __syncthreads();
        int b = 0;
        for (int k0 = 32; k0 < 2048; k0 += 32) {
            STAGE_T(b ^ 1, k0);
            COMPUTE_T(b);
            __syncthreads();
            b ^= 1;
        }
        COMPUTE_T(b);

        u16* yy = kh ? y1b : y0b;
        const int rb4 = (lane >> 4) * 4;
        const int colbase = n0 + wc * 64 + lane15;
        float bias[4];
        #pragma unroll
        for (int ni = 0; ni < 4; ni++) bias[ni] = kh ? 0.f : b2[e * 1024 + colbase + ni * 16];
        #pragma unroll
        for (int mi = 0; mi < 4; mi++) {
            #pragma unroll
            for (int j = 0; j < 4; j++) {
                const int lrow = wr * 64 + mi * 16 + rb4 + j;
                if (row0 + lrow < cnt) {
                    const size_t gr = (size_t)(off + row0 + lrow);
                    #pragma unroll
                    for (int ni = 0; ni < 4; ni++)
                        yy[gr * 1024 + colbase + ni * 16] = f2bf(acc[mi][ni][j] + bias[ni]);
                }
            }
        }
    }
}

// ---------------- K7: combine (w0*(y0+y1) + residual) + LayerNorm ----------------
__global__ __launch_bounds__(256) void k_combine(
    const float* __restrict__ x, const u16* __restrict__ y0b, const u16* __restrict__ y1b,
    const int* __restrict__ pos_of, const float* __restrict__ wgt,
    const float* __restrict__ gamma, const float* __restrict__ beta,
    float* __restrict__ out)
{
    const int t = blockIdx.x;
    const int tid = threadIdx.x;
    const int p0 = pos_of[2 * t], p1 = pos_of[2 * t + 1];
    const float w0 = wgt[2 * t], w1 = wgt[2 * t + 1];
    const int j4 = tid * 4;
    const float4 xv = *(const float4*)(x + (size_t)t * 1024 + j4);
    const ushort4 ua0 = *(const ushort4*)(y0b + (size_t)p0 * 1024 + j4);
    const ushort4 ub0 = *(const ushort4*)(y1b + (size_t)p0 * 1024 + j4);
    const ushort4 ua1 = *(const ushort4*)(y0b + (size_t)p1 * 1024 + j4);
    const ushort4 ub1 = *(const ushort4*)(y1b + (size_t)p1 * 1024 + j4);
    float a0 = xv.x + w0 * (bf2f(ua0.x) + bf2f(ub0.x)) + w1 * (bf2f(ua1.x) + bf2f(ub1.x));
    float a1 = xv.y + w0 * (bf2f(ua0.y) + bf2f(ub0.y)) + w1 * (bf2f(ua1.y) + bf2f(ub1.y));
    float a2 = xv.z + w0 * (bf2f(ua0.z) + bf2f(ub0.z)) + w1 * (bf2f(ua1.z) + bf2f(ub1.z));
    float a3 = xv.w + w0 * (bf2f(ua0.w) + bf2f(ub0.w)) + w1 * (bf2f(ua1.w) + bf2f(ub1.w));
    float s = a0 + a1 + a2 + a3;
    float q = a0 * a0 + a1 * a1 + a2 * a2 + a3 * a3;
    #pragma unroll
    for (int o = 32; o; o >>= 1) { s += __shfl_xor(s, o); q += __shfl_xor(q, o); }
    __shared__ float ls[4], lq[4];
    const int wav = tid >> 6, lane = tid & 63;
    if (lane == 0) { ls[wav] = s; lq[wav] = q; }
    __syncthreads();
    s = ls[0] + ls[1] + ls[2] + ls[3];
    q = lq[0] + lq[1] + lq[2] + lq[3];
    const float mu = s * (1.0f / 1024.0f);
    const float var = q * (1.0f / 1024.0f) - mu * mu;
    const float rs = rsqrtf(var + 1e-5f);
    const float4 g = *(const float4*)(gamma + j4);
    const float4 b = *(const float4*)(beta + j4);
    float4 o4;
    o4.x = (a0 - mu) * rs * g.x + b.x;
    o4.y = (a1 - mu) * rs * g.y + b.y;
    o4.z = (a2 - mu) * rs * g.z + b.z;
    o4.w = (a3 - mu) * rs * g.w + b.w;
    *(float4*)(out + (size_t)t * 1024 + j4) = o4;
}

extern "C" void kernel_launch(void* const* d_in, const int* in_sizes, int n_in,
                              void* d_out, int out_size, void* d_ws, size_t ws_size,
                              hipStream_t stream) {
    const float* x     = (const float*)d_in[0];   // [2,2048,1024]
    const float* rw    = (const float*)d_in[1];   // [8,1024]
    const float* rb    = (const float*)d_in[2];   // [8]
    const float* W1    = (const float*)d_in[3];   // [8,1024,4096]
    const float* b1    = (const float*)d_in[4];   // [8,4096]
    const float* W2    = (const float*)d_in[5];   // [8,4096,1024]
    const float* b2    = (const float*)d_in[6];   // [8,1024]
    const float* gamma = (const float*)d_in[7];   // [1024]
    const float* beta  = (const float*)d_in[8];   // [1024]
    float* out = (float*)d_out;

    // workspace carve (256B aligned)
    char* p = (char*)d_ws;
    auto alloc = [&](size_t bytes) { char* r = p; p += (bytes + 255) & ~(size_t)255; return r; };
    int*   ctrl    = (int*)alloc(32 * sizeof(int));  // counts[0..7] cursors[8..15] g1cur[16..23] g2cur[24..31]
    int*   counts  = ctrl;
    int*   cursors = ctrl + 8;
    int*   g1cur   = ctrl + 16;
    int*   g2cur   = ctrl + 24;
    int*   offsets = (int*)alloc(9 * sizeof(int));
    int*   eidx    = (int*)alloc(8192 * sizeof(int));
    float* wgt     = (float*)alloc(8192 * sizeof(float));
    int*   pos_of  = (int*)alloc(8192 * sizeof(int));
    int*   rows    = (int*)alloc(8192 * sizeof(int));
    u16*   xb      = (u16*)alloc((size_t)4096 * 1024 * 2);
    u16*   W1t     = (u16*)alloc((size_t)8 * 4096 * 1024 * 2);   // 64MB; dead after gemm1
    u16*   W2t     = (u16*)alloc((size_t)8 * 1024 * 4096 * 2);
    u16*   hbuf    = (u16*)alloc((size_t)8192 * 4096 * 2);
    // y0/y1 (bf16, 16MB each) alias W1t (dead after gemm1)
    u16* y0b = W1t;
    u16* y1b = W1t + (size_t)8192 * 1024;

    hipLaunchKernelGGL(k_init, dim3(1), dim3(64), 0, stream, ctrl);
    hipLaunchKernelGGL(k_router, dim3(1024), dim3(256), 0, stream, x, rw, rb, xb, eidx, wgt, counts);
    hipLaunchKernelGGL(k_offsets, dim3(1), dim3(64), 0, stream, counts, offsets);
    hipLaunchKernelGGL(k_place, dim3(32), dim3(256), 0, stream, eidx, offsets, cursors, rows, pos_of);
    // W1 [E][1024][4096] -> W1t [E][4096][1024]
    hipLaunchKernelGGL(k_transp, dim3(64, 32, 8), dim3(256), 0, stream, W1, W1t, 1024, 4096);
    // W2 [E][4096][1024] -> W2t [E][1024][4096]
    hipLaunchKernelGGL(k_transp, dim3(16, 128, 8), dim3(256), 0, stream, W2, W2t, 4096, 1024);
    hipLaunchKernelGGL(k_gemm1, dim3(1024), dim3(256), 0, stream, xb, W1t, b1, hbuf, rows, offsets, g1cur);
    hipLaunchKernelGGL(k_gemm2, dim3(1024), dim3(256), 0, stream, hbuf, W2t, b2, y0b, y1b, offsets, g2cur);
    hipLaunchKernelGGL(k_combine, dim3(4096), dim3(256), 0, stream, x, y0b, y1b, pos_of, wgt, gamma, beta, out);
}

// Round 6
// 460.533 us; speedup vs baseline: 1.1858x; 1.1290x over previous
//
#include <hip/hip_runtime.h>
#include <hip/hip_bf16.h>

// MoE head: router(top2 of 8) -> compact -> GEMM1+GELU -> GEMM2(split-K) -> combine+residual+LN
// R6: R3 static-grid structure + (a) XOR bank swizzle (source-side, LDS dest linear),
//     (b) counted-vmcnt pipeline (s_barrier pairs, vmcnt(4) never 0 in loop),
//     (c) setprio around MFMA, (d) bf16 y partials aliased onto dead W1t.

typedef unsigned short u16;
typedef unsigned int u32;
typedef __attribute__((ext_vector_type(4))) float f32x4;
typedef __attribute__((ext_vector_type(8))) short s16x8;
typedef __attribute__((ext_vector_type(8))) unsigned short u16x8;

#define GLD16(gp, lp) __builtin_amdgcn_global_load_lds( \
    (const __attribute__((address_space(1))) void*)(gp), \
    (__attribute__((address_space(3))) void*)(lp), 16, 0, 0)

__device__ __forceinline__ u16 f2bf(float f) {
    union { float f; u32 u; } v; v.f = f;
    u32 u = v.u;
    return (u16)((u + 0x7fffu + ((u >> 16) & 1u)) >> 16);
}
__device__ __forceinline__ float bf2f(u16 h) {
    union { u32 u; float f; } v; v.u = ((u32)h) << 16; return v.f;
}

// fast GELU: v * sigmoid(1.59577v + 0.0713548v^3)
__device__ __forceinline__ float gelu_f(float v) {
    const float u = v * (0.7978845608f + 0.0356774081f * v * v);
    const float t = __expf(-2.0f * u);
    return v * __builtin_amdgcn_rcpf(1.0f + t);
}

// ---------------- K0: zero counts+cursors (16 ints) ----------------
__global__ void k_init(int* cc) { if (threadIdx.x < 16) cc[threadIdx.x] = 0; }

// ---------------- K1: router (fp32) + x->bf16 convert ----------------
__global__ __launch_bounds__(256) void k_router(
    const float* __restrict__ x, const float* __restrict__ rw, const float* __restrict__ rb,
    u16* __restrict__ xb, int* __restrict__ eidx, float* __restrict__ wgt, int* __restrict__ counts)
{
    const int wav = threadIdx.x >> 6, lane = threadIdx.x & 63;
    const int t = blockIdx.x * 4 + wav;
    const float* xt = x + (size_t)t * 1024;
    float acc[8] = {0.f,0.f,0.f,0.f,0.f,0.f,0.f,0.f};
    #pragma unroll
    for (int c = 0; c < 4; c++) {
        const int base = c * 256 + lane * 4;
        const float4 xv = *(const float4*)(xt + base);
        ushort4 pk;
        pk.x = f2bf(xv.x); pk.y = f2bf(xv.y); pk.z = f2bf(xv.z); pk.w = f2bf(xv.w);
        *(ushort4*)(xb + (size_t)t * 1024 + base) = pk;
        #pragma unroll
        for (int e = 0; e < 8; e++) {
            const float4 wv = *(const float4*)(rw + e * 1024 + base);
            acc[e] += xv.x * wv.x + xv.y * wv.y + xv.z * wv.z + xv.w * wv.w;
        }
    }
    #pragma unroll
    for (int e = 0; e < 8; e++) {
        #pragma unroll
        for (int s = 32; s; s >>= 1) acc[e] += __shfl_xor(acc[e], s);
    }
    if (lane == 0) {
        float v0 = -3e38f, v1 = -3e38f; int i0 = 0, i1 = 0;
        #pragma unroll
        for (int e = 0; e < 8; e++) {
            const float l = acc[e] + rb[e];
            if (l > v0) { v1 = v0; i1 = i0; v0 = l; i0 = e; }
            else if (l > v1) { v1 = l; i1 = e; }
        }
        const float w0 = 1.0f / (1.0f + expf(v1 - v0));
        eidx[2 * t] = i0; eidx[2 * t + 1] = i1;
        wgt[2 * t] = w0; wgt[2 * t + 1] = 1.0f - w0;
        atomicAdd(&counts[i0], 1); atomicAdd(&counts[i1], 1);
    }
}

// ---------------- K2: exclusive prefix of 8 counts ----------------
__global__ void k_offsets(const int* __restrict__ counts, int* __restrict__ offsets) {
    if (threadIdx.x == 0) {
        int s = 0;
        for (int e = 0; e < 8; e++) { offsets[e] = s; s += counts[e]; }
        offsets[8] = s;
    }
}

// ---------------- K3: place assignments into compacted row list ----------------
__global__ __launch_bounds__(256) void k_place(
    const int* __restrict__ eidx, const int* __restrict__ offsets, int* __restrict__ cursors,
    int* __restrict__ rows, int* __restrict__ pos_of)
{
    const int a = blockIdx.x * 256 + threadIdx.x;   // 8192 assignments
    const int e = eidx[a];
    const int pos = offsets[e] + atomicAdd(&cursors[e], 1);
    rows[pos] = a >> 1;
    pos_of[a] = pos;
}

// ---------------- K4: transpose + fp32->bf16 (per expert), no LDS ----------------
// src [E][R][C] f32 -> dst [E][C][R] bf16 ; grid (C/64, R/32, E), block 256
__global__ __launch_bounds__(256) void k_transp(
    const float* __restrict__ src, u16* __restrict__ dst, int R, int C)
{
    const int e = blockIdx.z;
    const float* s = src + (size_t)e * R * C;
    u16* d = dst + (size_t)e * R * C;
    const int c = blockIdx.x * 64 + (threadIdx.x >> 2);
    const int r0 = blockIdx.y * 32 + (threadIdx.x & 3) * 8;
    u16x8 v;
    #pragma unroll
    for (int k = 0; k < 8; k++)
        v[k] = f2bf(s[(size_t)(r0 + k) * C + c]);
    *(u16x8*)(d + (size_t)c * R + r0) = v;
}

// shared GEMM macros: LDS [2][128][32] bf16 per operand, linear dest;
// source column pre-swizzled (chunk ^= (row>>1)&3), read offset swizzled to match.
#define STAGE_T(b, k0) { \
    char* ad = (char*)At + (b) * 8192 + wav * 1024; \
    char* bd = (char*)Bt + (b) * 8192 + wav * 1024; \
    GLD16(a_src0 + (k0), ad); \
    GLD16(a_src1 + (k0), ad + 4096); \
    GLD16(b_src0 + (k0), bd); \
    GLD16(b_src1 + (k0), bd + 4096); }

#define COMPUTE_T(b) { \
    const u16* Abp = Ab + (b) * 4096; \
    const u16* Bbp = Bb + (b) * 4096; \
    s16x8 af[4], bfr[4]; \
    _Pragma("unroll") \
    for (int i = 0; i < 4; i++) { \
        af[i]  = *(const s16x8*)(Abp + i * 512); \
        bfr[i] = *(const s16x8*)(Bbp + i * 512); \
    } \
    __builtin_amdgcn_s_setprio(1); \
    _Pragma("unroll") \
    for (int mi = 0; mi < 4; mi++) \
        _Pragma("unroll") \
        for (int ni = 0; ni < 4; ni++) \
            acc[mi][ni] = __builtin_amdgcn_mfma_f32_16x16x32_bf16(af[mi], bfr[ni], acc[mi][ni], 0, 0, 0); \
    __builtin_amdgcn_s_setprio(0); }

#define VMCNT4 asm volatile("s_waitcnt vmcnt(4)" ::: "memory")
#define VMCNT0 asm volatile("s_waitcnt vmcnt(0)" ::: "memory")
#define BAR __builtin_amdgcn_s_barrier()

// ---------------- K5: grouped GEMM1 + bias + fast GELU -> h (bf16) ----------------
// 8192 blocks flat; swz -> (e, x=n-tile of 32, y=row-tile of 32, y fastest)
__global__ __launch_bounds__(256, 4) void k_gemm1(
    const u16* __restrict__ xb, const u16* __restrict__ W1t, const float* __restrict__ b1,
    u16* __restrict__ hbuf, const int* __restrict__ rows, const int* __restrict__ offsets)
{
    const int fid = blockIdx.x;
    const int swz = (fid & 7) * 1024 + (fid >> 3);   // bijective, nwg=8192
    const int y = swz & 31, xx = (swz >> 5) & 31, e = swz >> 10;

    const int off = offsets[e], cnt = offsets[e + 1] - off;
    const int row0 = y * 128;
    if (row0 >= cnt) return;
    const int n0 = xx * 128;
    const int tid = threadIdx.x;
    const int lane = tid & 63, wav = tid >> 6, lane15 = lane & 15;

    __shared__ u16 At[2][128][32];
    __shared__ u16 Bt[2][128][32];

    const int ar0 = tid >> 2;
    const int cl8 = (((tid & 3) ^ ((tid >> 3) & 3))) * 8;   // swizzled source chunk
    const int t0 = rows[off + min(row0 + ar0, cnt - 1)];
    const int t1 = rows[off + min(row0 + ar0 + 64, cnt - 1)];
    const u16* a_src0 = xb + (size_t)t0 * 1024 + cl8;
    const u16* a_src1 = xb + (size_t)t1 * 1024 + cl8;
    const u16* b_src0 = W1t + ((size_t)e * 4096 + n0 + ar0) * 1024 + cl8;
    const u16* b_src1 = b_src0 + (size_t)64 * 1024;

    f32x4 acc[4][4] = {};
    const int wr = wav >> 1, wc = wav & 1;
    const int koff = ((lane >> 4) ^ ((lane >> 1) & 3)) * 8;  // swizzled read chunk
    const u16* Ab = &At[0][wr * 64 + lane15][koff];
    const u16* Bb = &Bt[0][wc * 64 + lane15][koff];

    STAGE_T(0, 0);
    int b = 0;
    for (int k0 = 32; k0 < 1024; k0 += 32) {
        STAGE_T(b ^ 1, k0);
        VMCNT4;             // current buffer's 4 loads landed (next 4 stay in flight)
        BAR;
        COMPUTE_T(b);
        BAR;                // all waves done reading buffer b
        b ^= 1;
    }
    VMCNT0;
    BAR;
    COMPUTE_T(b);

    const int rb4 = (lane >> 4) * 4;
    const int colbase = n0 + wc * 64 + lane15;
    float bias[4];
    #pragma unroll
    for (int ni = 0; ni < 4; ni++) bias[ni] = b1[e * 4096 + colbase + ni * 16];
    #pragma unroll
    for (int mi = 0; mi < 4; mi++) {
        #pragma unroll
        for (int j = 0; j < 4; j++) {
            const int lrow = wr * 64 + mi * 16 + rb4 + j;
            if (row0 + lrow < cnt) {
                const size_t gr = (size_t)(off + row0 + lrow);
                #pragma unroll
                for (int ni = 0; ni < 4; ni++) {
                    const float v = acc[mi][ni][j] + bias[ni];
                    hbuf[gr * 4096 + colbase + ni * 16] = f2bf(gelu_f(v));
                }
            }
        }
    }
}

// ---------------- K6: grouped GEMM2 (split-K x2) + bias -> y0/y1 (bf16) ----------------
// 4096 blocks flat; swz -> (z=e*2+kh, x=n-tile of 8, y=row-tile of 32, y fastest)
__global__ __launch_bounds__(256, 4) void k_gemm2(
    const u16* __restrict__ hbuf, const u16* __restrict__ W2t, const float* __restrict__ b2,
    u16* __restrict__ y0b, u16* __restrict__ y1b, const int* __restrict__ offsets)
{
    const int fid = blockIdx.x;
    const int swz = (fid & 7) * 512 + (fid >> 3);    // bijective, nwg=4096
    const int y = swz & 31, xx = (swz >> 5) & 7, z = swz >> 8;
    const int e = z >> 1, kh = z & 1;

    const int off = offsets[e], cnt = offsets[e + 1] - off;
    const int row0 = y * 128;
    if (row0 >= cnt) return;
    const int n0 = xx * 128;
    const int tid = threadIdx.x;
    const int lane = tid & 63, wav = tid >> 6, lane15 = lane & 15;
    const int kbase = kh * 2048;

    __shared__ u16 At[2][128][32];
    __shared__ u16 Bt[2][128][32];

    const int ar0 = tid >> 2;
    const int cl8 = (((tid & 3) ^ ((tid >> 3) & 3))) * 8;
    const u16* a_src0 = hbuf + (size_t)(off + min(row0 + ar0, cnt - 1)) * 4096 + kbase + cl8;
    const u16* a_src1 = hbuf + (size_t)(off + min(row0 + ar0 + 64, cnt - 1)) * 4096 + kbase + cl8;
    const u16* b_src0 = W2t + ((size_t)e * 1024 + n0 + ar0) * 4096 + kbase + cl8;
    const u16* b_src1 = b_src0 + (size_t)64 * 4096;

    f32x4 acc[4][4] = {};
    const int wr = wav >> 1, wc = wav & 1;
    const int koff = ((lane >> 4) ^ ((lane >> 1) & 3)) * 8;
    const u16* Ab = &At[0][wr * 64 + lane15][koff];
    const u16* Bb = &Bt[0][wc * 64 + lane15][koff];

    STAGE_T(0, 0);
    int b = 0;
    for (int k0 = 32; k0 < 2048; k0 += 32) {
        STAGE_T(b ^ 1, k0);
        VMCNT4;
        BAR;
        COMPUTE_T(b);
        BAR;
        b ^= 1;
    }
    VMCNT0;
    BAR;
    COMPUTE_T(b);

    u16* yy = kh ? y1b : y0b;
    const int rb4 = (lane >> 4) * 4;
    const int colbase = n0 + wc * 64 + lane15;
    float bias[4];
    #pragma unroll
    for (int ni = 0; ni < 4; ni++) bias[ni] = kh ? 0.f : b2[e * 1024 + colbase + ni * 16];
    #pragma unroll
    for (int mi = 0; mi < 4; mi++) {
        #pragma unroll
        for (int j = 0; j < 4; j++) {
            const int lrow = wr * 64 + mi * 16 + rb4 + j;
            if (row0 + lrow < cnt) {
                const size_t gr = (size_t)(off + row0 + lrow);
                #pragma unroll
                for (int ni = 0; ni < 4; ni++)
                    yy[gr * 1024 + colbase + ni * 16] = f2bf(acc[mi][ni][j] + bias[ni]);
            }
        }
    }
}

// ---------------- K7: combine (w0*(y0+y1) + residual) + LayerNorm ----------------
__global__ __launch_bounds__(256) void k_combine(
    const float* __restrict__ x, const u16* __restrict__ y0b, const u16* __restrict__ y1b,
    const int* __restrict__ pos_of, const float* __restrict__ wgt,
    const float* __restrict__ gamma, const float* __restrict__ beta,
    float* __restrict__ out)
{
    const int t = blockIdx.x;
    const int tid = threadIdx.x;
    const int p0 = pos_of[2 * t], p1 = pos_of[2 * t + 1];
    const float w0 = wgt[2 * t], w1 = wgt[2 * t + 1];
    const int j4 = tid * 4;
    const float4 xv = *(const float4*)(x + (size_t)t * 1024 + j4);
    const ushort4 ua0 = *(const ushort4*)(y0b + (size_t)p0 * 1024 + j4);
    const ushort4 ub0 = *(const ushort4*)(y1b + (size_t)p0 * 1024 + j4);
    const ushort4 ua1 = *(const ushort4*)(y0b + (size_t)p1 * 1024 + j4);
    const ushort4 ub1 = *(const ushort4*)(y1b + (size_t)p1 * 1024 + j4);
    float a0 = xv.x + w0 * (bf2f(ua0.x) + bf2f(ub0.x)) + w1 * (bf2f(ua1.x) + bf2f(ub1.x));
    float a1 = xv.y + w0 * (bf2f(ua0.y) + bf2f(ub0.y)) + w1 * (bf2f(ua1.y) + bf2f(ub1.y));
    float a2 = xv.z + w0 * (bf2f(ua0.z) + bf2f(ub0.z)) + w1 * (bf2f(ua1.z) + bf2f(ub1.z));
    float a3 = xv.w + w0 * (bf2f(ua0.w) + bf2f(ub0.w)) + w1 * (bf2f(ua1.w) + bf2f(ub1.w));
    float s = a0 + a1 + a2 + a3;
    float q = a0 * a0 + a1 * a1 + a2 * a2 + a3 * a3;
    #pragma unroll
    for (int o = 32; o; o >>= 1) { s += __shfl_xor(s, o); q += __shfl_xor(q, o); }
    __shared__ float ls[4], lq[4];
    const int wav = tid >> 6, lane = tid & 63;
    if (lane == 0) { ls[wav] = s; lq[wav] = q; }
    __syncthreads();
    s = ls[0] + ls[1] + ls[2] + ls[3];
    q = lq[0] + lq[1] + lq[2] + lq[3];
    const float mu = s * (1.0f / 1024.0f);
    const float var = q * (1.0f / 1024.0f) - mu * mu;
    const float rs = rsqrtf(var + 1e-5f);
    const float4 g = *(const float4*)(gamma + j4);
    const float4 b = *(const float4*)(beta + j4);
    float4 o4;
    o4.x = (a0 - mu) * rs * g.x + b.x;
    o4.y = (a1 - mu) * rs * g.y + b.y;
    o4.z = (a2 - mu) * rs * g.z + b.z;
    o4.w = (a3 - mu) * rs * g.w + b.w;
    *(float4*)(out + (size_t)t * 1024 + j4) = o4;
}

extern "C" void kernel_launch(void* const* d_in, const int* in_sizes, int n_in,
                              void* d_out, int out_size, void* d_ws, size_t ws_size,
                              hipStream_t stream) {
    const float* x     = (const float*)d_in[0];   // [2,2048,1024]
    const float* rw    = (const float*)d_in[1];   // [8,1024]
    const float* rb    = (const float*)d_in[2];   // [8]
    const float* W1    = (const float*)d_in[3];   // [8,1024,4096]
    const float* b1    = (const float*)d_in[4];   // [8,4096]
    const float* W2    = (const float*)d_in[5];   // [8,4096,1024]
    const float* b2    = (const float*)d_in[6];   // [8,1024]
    const float* gamma = (const float*)d_in[7];   // [1024]
    const float* beta  = (const float*)d_in[8];   // [1024]
    float* out = (float*)d_out;

    // workspace carve (256B aligned)
    char* p = (char*)d_ws;
    auto alloc = [&](size_t bytes) { char* r = p; p += (bytes + 255) & ~(size_t)255; return r; };
    int*   counts  = (int*)alloc(16 * sizeof(int));      // counts[0..7], cursors[8..15]
    int*   cursors = counts + 8;
    int*   offsets = (int*)alloc(9 * sizeof(int));
    int*   eidx    = (int*)alloc(8192 * sizeof(int));
    float* wgt     = (float*)alloc(8192 * sizeof(float));
    int*   pos_of  = (int*)alloc(8192 * sizeof(int));
    int*   rows    = (int*)alloc(8192 * sizeof(int));
    u16*   xb      = (u16*)alloc((size_t)4096 * 1024 * 2);
    u16*   W1t     = (u16*)alloc((size_t)8 * 4096 * 1024 * 2);   // 64MB; dead after gemm1
    u16*   W2t     = (u16*)alloc((size_t)8 * 1024 * 4096 * 2);
    u16*   hbuf    = (u16*)alloc((size_t)8192 * 4096 * 2);
    // y0/y1 (bf16, 16MB each) alias W1t (dead after gemm1)
    u16* y0b = W1t;
    u16* y1b = W1t + (size_t)8192 * 1024;

    hipLaunchKernelGGL(k_init, dim3(1), dim3(64), 0, stream, counts);
    hipLaunchKernelGGL(k_router, dim3(1024), dim3(256), 0, stream, x, rw, rb, xb, eidx, wgt, counts);
    hipLaunchKernelGGL(k_offsets, dim3(1), dim3(64), 0, stream, counts, offsets);
    hipLaunchKernelGGL(k_place, dim3(32), dim3(256), 0, stream, eidx, offsets, cursors, rows, pos_of);
    // W1 [E][1024][4096] -> W1t [E][4096][1024]
    hipLaunchKernelGGL(k_transp, dim3(64, 32, 8), dim3(256), 0, stream, W1, W1t, 1024, 4096);
    // W2 [E][4096][1024] -> W2t [E][1024][4096]
    hipLaunchKernelGGL(k_transp, dim3(16, 128, 8), dim3(256), 0, stream, W2, W2t, 4096, 1024);
    hipLaunchKernelGGL(k_gemm1, dim3(8192), dim3(256), 0, stream, xb, W1t, b1, hbuf, rows, offsets);
    hipLaunchKernelGGL(k_gemm2, dim3(4096), dim3(256), 0, stream, hbuf, W2t, b2, y0b, y1b, offsets);
    hipLaunchKernelGGL(k_combine, dim3(4096), dim3(256), 0, stream, x, y0b, y1b, pos_of, wgt, gamma, beta, out);
}